// Round 6
// baseline (264.310 us; speedup 1.0000x reference)
//
#include <hip/hip_runtime.h>
#include <cmath>

#define NQ 16
#define NT 8

typedef float f32x4 __attribute__((ext_vector_type(4)));

// order-preserving float->u32 (total order ascending)
__device__ __forceinline__ unsigned ordf(float x) {
    unsigned u = __float_as_uint(x);
    return u ^ ((unsigned)((int)u >> 31) | 0x80000000u);
}
// inverse (keys here are always real query keys, never the empty sentinel)
__device__ __forceinline__ float unordf(unsigned k) {
    unsigned m = (~(unsigned)((int)k >> 31)) | 0x80000000u;
    return __uint_as_float(k ^ m);
}
__device__ __forceinline__ unsigned umin2(unsigned a, unsigned b) { return a < b ? a : b; }

// Intra-quad lane exchange via DPP quad_perm — single VALU op, no LDS pipe.
// xor1: [1,0,3,2] = 0xB1;  xor2: [2,3,0,1] = 0x4E.
__device__ __forceinline__ unsigned dpp_xor1_u(unsigned x) {
    return (unsigned)__builtin_amdgcn_mov_dpp((int)x, 0xB1, 0xF, 0xF, true);
}
__device__ __forceinline__ unsigned dpp_xor2_u(unsigned x) {
    return (unsigned)__builtin_amdgcn_mov_dpp((int)x, 0x4E, 0xF, 0xF, true);
}
__device__ __forceinline__ float dpp_xor1_f(float x) {
    return __uint_as_float(dpp_xor1_u(__float_as_uint(x)));
}

// Exact reference-parity path (rare): recompute the whole row with the
// correctly-rounded double-exp sigmoid and exact float dedup (validated
// bit-exact vs reference, absmax 0.0). Unchanged.
__device__ __noinline__ unsigned exact_mask(
    const float* __restrict__ pred_logits,
    const float* __restrict__ pred_disp,
    const float* __restrict__ targets,
    size_t b)
{
    float tg[NT];
#pragma unroll
    for (int t = 0; t < NT; ++t) {
        float v = targets[b * NT + t];
        tg[t] = (v == 0.0f) ? 1000000.0f : v;
    }
    float C[NQ];
    int   ind[NQ];
#pragma unroll
    for (int n = 0; n < NQ; ++n) {
        float d = pred_disp[b * NQ + n];
        float best = fabsf(d - tg[0]);
        int bi = 0;
#pragma unroll
        for (int t = 1; t < NT; ++t) {
            float e = fabsf(d - tg[t]);
            if (e < best) { best = e; bi = t; }   // strict <: first target wins
        }
        float sig = (float)(1.0 / (1.0 + exp(-(double)pred_logits[b * NQ + n])));
        C[n] = (-sig) + best;                     // same op order as reference
        ind[n] = bi;
    }
    unsigned mask = 0u;
#pragma unroll
    for (int t = 0; t < NT; ++t) {
        int w = 31;
        float bc = 3.0e38f;
#pragma unroll
        for (int n = 0; n < NQ; ++n) {
            bool upd = (ind[n] == t) && (C[n] < bc);  // strict <: first query wins
            bc = upd ? C[n] : bc;
            w  = upd ? n : w;
        }
        mask |= (1u << w);
    }
    return mask;
}

struct QuadOut { f32x4 oi, ol; };

// One quad-lane's worth of work for one row (validated round-3 body).
// Query-centric dedup: per-target BEST keys only (named scalars, never
// arrays -> nothing demoted to LDS/scratch), butterfly-min over the quad
// via DPP; label = (my key == best of my target). Guard: non-winner within
// thr of its target's best fires need_slow (equivalent to the validated
// best/2nd-best gap guard); OR-reduced so the branch is quad-uniform.
__device__ __forceinline__ QuadOut quad_compute(
    int j, size_t b, f32x4 d4, f32x4 l4, f32x4 t4,
    const float* __restrict__ pred_logits,
    const float* __restrict__ pred_disp,
    const float* __restrict__ targets)
{
    const float BIGF = 1000000.0f;

    // sentinel-replace my half of targets, swap halves across lane^1 (DPP)
    float tv0 = (t4.x == 0.0f) ? BIGF : t4.x;
    float tv1 = (t4.y == 0.0f) ? BIGF : t4.y;
    float tv2 = (t4.z == 0.0f) ? BIGF : t4.z;
    float tv3 = (t4.w == 0.0f) ? BIGF : t4.w;
    float ov0 = dpp_xor1_f(tv0);
    float ov1 = dpp_xor1_f(tv1);
    float ov2 = dpp_xor1_f(tv2);
    float ov3 = dpp_xor1_f(tv3);

    const bool lo = ((j & 1) == 0);
    float tg[NT];
    tg[0] = lo ? tv0 : ov0;  tg[1] = lo ? tv1 : ov1;
    tg[2] = lo ? tv2 : ov2;  tg[3] = lo ? tv3 : ov3;
    tg[4] = lo ? ov0 : tv0;  tg[5] = lo ? ov1 : tv1;
    tg[6] = lo ? ov2 : tv2;  tg[7] = lo ? ov3 : tv3;

    // my 4 queries: exact argmin over 8 targets + fast-sigmoid key
    int      ind[4];
    unsigned qk[4];
    {
        float dv[4] = {d4.x, d4.y, d4.z, d4.w};
        float lv[4] = {l4.x, l4.y, l4.z, l4.w};
#pragma unroll
        for (int i = 0; i < 4; ++i) {
            float d = dv[i];
            float best = fabsf(d - tg[0]);
            int bi = 0;
#pragma unroll
            for (int t = 1; t < NT; ++t) {
                float e = fabsf(d - tg[t]);
                if (e < best) { best = e; bi = t; }   // exact: matches reference
            }
            ind[i] = bi;
            float sig = __builtin_amdgcn_rcpf(1.0f + __expf(-lv[i]));
            float C = best - sig;
            int n = 4 * j + i;                        // global query id
            qk[i] = (ordf(C) & ~31u) | (unsigned)n;   // key: C order + query id
        }
    }

    // per-target best over my 4 queries (min-only, named scalars)
    auto localbest = [&](int t) -> unsigned {
        unsigned bc = 0xFFFFFFFFu;
#pragma unroll
        for (int i = 0; i < 4; ++i) {
            unsigned x = (ind[i] == t) ? qk[i] : 0xFFFFFFFFu;
            bc = umin2(bc, x);
        }
        return bc;
    };
    unsigned bc0 = localbest(0), bc1 = localbest(1);
    unsigned bc2 = localbest(2), bc3 = localbest(3);
    unsigned bc4 = localbest(4), bc5 = localbest(5);
    unsigned bc6 = localbest(6), bc7 = localbest(7);

    // butterfly min over the quad: 2 DPP + 2 min per target
    auto quadmin = [](unsigned v) -> unsigned {
        v = umin2(v, dpp_xor1_u(v));
        v = umin2(v, dpp_xor2_u(v));
        return v;
    };
    bc0 = quadmin(bc0); bc1 = quadmin(bc1);
    bc2 = quadmin(bc2); bc3 = quadmin(bc3);
    bc4 = quadmin(bc4); bc5 = quadmin(bc5);
    bc6 = quadmin(bc6); bc7 = quadmin(bc7);

    // select bc[ind[i]] via 3-level cndmask tree (scalars only)
    auto selbc = [&](int id) -> unsigned {
        unsigned a0 = (id & 1) ? bc1 : bc0;
        unsigned a1 = (id & 1) ? bc3 : bc2;
        unsigned a2 = (id & 1) ? bc5 : bc4;
        unsigned a3 = (id & 1) ? bc7 : bc6;
        unsigned c0 = (id & 2) ? a1 : a0;
        unsigned c1 = (id & 2) ? a3 : a2;
        return (id & 4) ? c1 : c0;
    };

    bool  ns = false;
    float lab0, lab1, lab2, lab3;
    {
        float labs[4];
#pragma unroll
        for (int i = 0; i < 4; ++i) {
            unsigned bsel = selbc(ind[i]);
            bool isw = (qk[i] == bsel);
            // guard in float domain: non-winner within thr of its target's
            // best -> ambiguous under fast sigmoid + 5-bit key clearing.
            float Cf  = unordf(qk[i]);
            float bf  = unordf(bsel);
            float thr = fmaf(fabsf(bf), 1.6e-5f, 2.0e-4f);
            ns = ns || (!isw && ((Cf - bf) < thr));
            labs[i] = isw ? 1.0f : 0.0f;
        }
        lab0 = labs[0]; lab1 = labs[1]; lab2 = labs[2]; lab3 = labs[3];
    }

    // OR-reduce need_slow over the quad -> uniform branch, no divergence
    unsigned nsw = ns ? 1u : 0u;
    nsw |= dpp_xor1_u(nsw);
    nsw |= dpp_xor2_u(nsw);
    if (__builtin_expect(nsw != 0u, 0)) {
        unsigned mask = exact_mask(pred_logits, pred_disp, targets, b);
        lab0 = (float)((mask >> (4 * j + 0)) & 1u);
        lab1 = (float)((mask >> (4 * j + 1)) & 1u);
        lab2 = (float)((mask >> (4 * j + 2)) & 1u);
        lab3 = (float)((mask >> (4 * j + 3)) & 1u);
    }

    QuadOut o;
    o.oi.x = (float)ind[0]; o.oi.y = (float)ind[1];
    o.oi.z = (float)ind[2]; o.oi.w = (float)ind[3];
    o.ol.x = lab0; o.ol.y = lab1; o.ol.z = lab2; o.ol.w = lab3;
    return o;
}

__device__ __forceinline__ void load_quad(
    size_t g, const float* __restrict__ pd, const float* __restrict__ pl,
    const float* __restrict__ pt, f32x4& d4, f32x4& l4, f32x4& t4)
{
    d4 = ((const f32x4*)pd)[g];
    l4 = ((const f32x4*)pl)[g];
    t4 = ((const f32x4*)pt)[(g >> 2) * 2 + (size_t)(g & 1)];
}

__device__ __forceinline__ void compute_store(
    size_t g, f32x4 d4, f32x4 l4, f32x4 t4,
    const float* __restrict__ pl, const float* __restrict__ pd,
    const float* __restrict__ pt,
    float* __restrict__ oi, float* __restrict__ ol)
{
    QuadOut q = quad_compute((int)(g & 3), g >> 2, d4, l4, t4, pl, pd, pt);
    ((f32x4*)oi)[g] = q.oi;
    ((f32x4*)ol)[g] = q.ol;
}

// PERSISTENT grid-stride kernel. Rationale (rounds 0-5 evidence):
//  - OccupancyPercent pinned at ~41% with zero resource pressure in every
//    variant -> 65536 short-lived waves churn through SPI; residency never
//    fills. Persistent grid: 2048 blocks = 8 blocks/CU, 8192 waves total,
//    launched once — residency should rise toward the cap.
//  - Depth-1 software pipeline with TWO NAMED register banks (A/B): the
//    prefetch for the next chunk is issued BEFORE the other bank's compute
//    inside the same iteration, so 3 loads are in flight under every
//    compute phase. In loop form the consuming compute sits BEHIND the
//    prefetch, so the compiler has no sinking incentive (unlike the
//    straight-line rounds 4/5 where VGPR=44 proved the loads got sunk).
//  - Stride is a multiple of 256 -> quad alignment and the proven 16 B/lane
//    contiguous coalescing are preserved at every iteration.
//  - Compute body is the validated round-3 quad_compute, untouched.
__global__ __launch_bounds__(256) void nearest_matcher_kernel(
    const float* __restrict__ pred_logits,
    const float* __restrict__ pred_disp,
    const float* __restrict__ targets,
    float* __restrict__ out_idx,
    float* __restrict__ out_lab,
    unsigned long long total,
    unsigned long long stride)
{
    size_t gA = (size_t)blockIdx.x * blockDim.x + threadIdx.x;
    if (gA >= (size_t)total) return;

    f32x4 dA, lA, tA;
    f32x4 dB = {0,0,0,0}, lB = {0,0,0,0}, tB = {0,0,0,0};

    load_quad(gA, pred_disp, pred_logits, targets, dA, lA, tA);
    size_t gB = gA + (size_t)stride;
    bool hB = gB < (size_t)total;
    if (hB) load_quad(gB, pred_disp, pred_logits, targets, dB, lB, tB);
    __builtin_amdgcn_sched_barrier(0);

    for (;;) {
        // compute bank A (bank B's loads in flight underneath)
        compute_store(gA, dA, lA, tA, pred_logits, pred_disp, targets,
                      out_idx, out_lab);
        if (!hB) break;

        // prefetch next chunk into bank A (now free)
        size_t gA2 = gB + (size_t)stride;
        bool hA2 = gA2 < (size_t)total;
        if (hA2) load_quad(gA2, pred_disp, pred_logits, targets, dA, lA, tA);
        __builtin_amdgcn_sched_barrier(0);

        // compute bank B (bank A's loads in flight underneath)
        compute_store(gB, dB, lB, tB, pred_logits, pred_disp, targets,
                      out_idx, out_lab);
        if (!hA2) break;

        // prefetch next chunk into bank B
        gA = gA2;
        gB = gA2 + (size_t)stride;
        hB = gB < (size_t)total;
        if (hB) load_quad(gB, pred_disp, pred_logits, targets, dB, lB, tB);
        __builtin_amdgcn_sched_barrier(0);
    }
}

extern "C" void kernel_launch(void* const* d_in, const int* in_sizes, int n_in,
                              void* d_out, int out_size, void* d_ws, size_t ws_size,
                              hipStream_t stream) {
    const float* pred_logits = (const float*)d_in[0];
    const float* pred_disp   = (const float*)d_in[1];
    const float* targets     = (const float*)d_in[2];

    int B = in_sizes[0] / NQ;

    float* out_idx = (float*)d_out;              // indices [B, NQ] flat, first
    float* out_lab = out_idx + (size_t)B * NQ;   // labels  [B, NQ] flat, second

    const unsigned long long total = (unsigned long long)B * 4;  // quad-lanes
    const int threads = 256;
    unsigned long long nb = (total + threads - 1) / threads;
    if (nb > 2048ull) nb = 2048ull;              // 8 blocks/CU x 256 CUs
    const unsigned long long stride = nb * (unsigned long long)threads;

    hipLaunchKernelGGL(nearest_matcher_kernel, dim3((unsigned)nb), dim3(threads),
                       0, stream,
                       pred_logits, pred_disp, targets, out_idx, out_lab,
                       total, stride);
}

// Round 7
// 259.677 us; speedup vs baseline: 1.0178x; 1.0178x over previous
//
#include <hip/hip_runtime.h>
#include <cmath>

#define NQ 16
#define NT 8

typedef float f32x4 __attribute__((ext_vector_type(4)));

// order-preserving float->u32 (total order ascending)
__device__ __forceinline__ unsigned ordf(float x) {
    unsigned u = __float_as_uint(x);
    return u ^ ((unsigned)((int)u >> 31) | 0x80000000u);
}
// inverse (keys here are always real query keys, never the empty sentinel)
__device__ __forceinline__ float unordf(unsigned k) {
    unsigned m = (~(unsigned)((int)k >> 31)) | 0x80000000u;
    return __uint_as_float(k ^ m);
}
__device__ __forceinline__ unsigned umin2(unsigned a, unsigned b) { return a < b ? a : b; }

// Intra-quad lane exchange via DPP quad_perm — single VALU op, no LDS pipe.
// xor1: [1,0,3,2] = 0xB1;  xor2: [2,3,0,1] = 0x4E.
__device__ __forceinline__ unsigned dpp_xor1_u(unsigned x) {
    return (unsigned)__builtin_amdgcn_mov_dpp((int)x, 0xB1, 0xF, 0xF, true);
}
__device__ __forceinline__ unsigned dpp_xor2_u(unsigned x) {
    return (unsigned)__builtin_amdgcn_mov_dpp((int)x, 0x4E, 0xF, 0xF, true);
}
__device__ __forceinline__ float dpp_xor1_f(float x) {
    return __uint_as_float(dpp_xor1_u(__float_as_uint(x)));
}

// Exact reference-parity path (rare): recompute the whole row with the
// correctly-rounded double-exp sigmoid and exact float dedup (validated
// bit-exact vs reference, absmax 0.0). Unchanged.
__device__ __noinline__ unsigned exact_mask(
    const float* __restrict__ pred_logits,
    const float* __restrict__ pred_disp,
    const float* __restrict__ targets,
    size_t b)
{
    float tg[NT];
#pragma unroll
    for (int t = 0; t < NT; ++t) {
        float v = targets[b * NT + t];
        tg[t] = (v == 0.0f) ? 1000000.0f : v;
    }
    float C[NQ];
    int   ind[NQ];
#pragma unroll
    for (int n = 0; n < NQ; ++n) {
        float d = pred_disp[b * NQ + n];
        float best = fabsf(d - tg[0]);
        int bi = 0;
#pragma unroll
        for (int t = 1; t < NT; ++t) {
            float e = fabsf(d - tg[t]);
            if (e < best) { best = e; bi = t; }   // strict <: first target wins
        }
        float sig = (float)(1.0 / (1.0 + exp(-(double)pred_logits[b * NQ + n])));
        C[n] = (-sig) + best;                     // same op order as reference
        ind[n] = bi;
    }
    unsigned mask = 0u;
#pragma unroll
    for (int t = 0; t < NT; ++t) {
        int w = 31;
        float bc = 3.0e38f;
#pragma unroll
        for (int n = 0; n < NQ; ++n) {
            bool upd = (ind[n] == t) && (C[n] < bc);  // strict <: first query wins
            bc = upd ? C[n] : bc;
            w  = upd ? n : w;
        }
        mask |= (1u << w);
    }
    return mask;
}

// FOUR lanes per row (proven layout: every global load/store is 16 B/lane
// perfectly contiguous). Lane j of a quad owns queries 4j..4j+3.
//
// SINGLE-VARIABLE EXPERIMENT vs round 3: block size 256 -> 1024.
// Evidence trail: OccupancyPercent reads ~3.3 WORKGROUPS/CU in every launch
// shape tried (16k/32k/2k-persistent blocks), independent of VGPR (44-60)
// and LDS (0). If the residency cap is per-CU workgroup slots, waves/CU =
// 3.3 x waves-per-wg: at 256 threads that's ~13 waves (measured), at 1024
// threads it's ~53 -> clips at the 32-wave cap = ~2.5x resident waves,
// which is the concurrency this latency-bound kernel has been starved of.
// Compute body is the validated round-3 source, untouched (absmax 0.0).
__global__ __launch_bounds__(1024) void nearest_matcher_kernel(
    const float* __restrict__ pred_logits,
    const float* __restrict__ pred_disp,
    const float* __restrict__ targets,
    float* __restrict__ out_idx,
    float* __restrict__ out_lab,
    int B)
{
    const size_t gid = (size_t)blockIdx.x * blockDim.x + threadIdx.x;
    const size_t b   = gid >> 2;          // row
    const int    j   = (int)(gid & 3);    // lane-in-quad: owns queries 4j..4j+3
    if (b >= (size_t)B) return;

    const float BIGF = 1000000.0f;

    // ---- coalesced loads: 16 B/lane, consecutive lanes consecutive addrs ----
    f32x4 d4 = ((const f32x4*)pred_disp)[gid];
    f32x4 l4 = ((const f32x4*)pred_logits)[gid];
    f32x4 t4 = ((const f32x4*)targets)[b * 2 + (size_t)(j & 1)];  // half (j&1)

    // sentinel-replace my half, then swap halves across lane^1 (DPP)
    float tv0 = (t4.x == 0.0f) ? BIGF : t4.x;
    float tv1 = (t4.y == 0.0f) ? BIGF : t4.y;
    float tv2 = (t4.z == 0.0f) ? BIGF : t4.z;
    float tv3 = (t4.w == 0.0f) ? BIGF : t4.w;
    float ov0 = dpp_xor1_f(tv0);
    float ov1 = dpp_xor1_f(tv1);
    float ov2 = dpp_xor1_f(tv2);
    float ov3 = dpp_xor1_f(tv3);

    const bool lo = ((j & 1) == 0);
    float tg[NT];
    tg[0] = lo ? tv0 : ov0;  tg[1] = lo ? tv1 : ov1;
    tg[2] = lo ? tv2 : ov2;  tg[3] = lo ? tv3 : ov3;
    tg[4] = lo ? ov0 : tv0;  tg[5] = lo ? ov1 : tv1;
    tg[6] = lo ? ov2 : tv2;  tg[7] = lo ? ov3 : tv3;

    // ---- my 4 queries: exact argmin over 8 targets + fast-sigmoid key ----
    int      ind[4];
    unsigned qk[4];
    {
        float dv[4] = {d4.x, d4.y, d4.z, d4.w};
        float lv[4] = {l4.x, l4.y, l4.z, l4.w};
#pragma unroll
        for (int i = 0; i < 4; ++i) {
            float d = dv[i];
            float best = fabsf(d - tg[0]);
            int bi = 0;
#pragma unroll
            for (int t = 1; t < NT; ++t) {
                float e = fabsf(d - tg[t]);
                if (e < best) { best = e; bi = t; }   // exact: matches reference
            }
            ind[i] = bi;
            float sig = __builtin_amdgcn_rcpf(1.0f + __expf(-lv[i]));
            float C = best - sig;
            int n = 4 * j + i;                        // global query id
            qk[i] = (ordf(C) & ~31u) | (unsigned)n;   // key: C order + query id
        }
    }

    // ---- per-target best over my 4 queries (min-only, named scalars) ----
    auto localbest = [&](int t) -> unsigned {
        unsigned bc = 0xFFFFFFFFu;
#pragma unroll
        for (int i = 0; i < 4; ++i) {
            unsigned x = (ind[i] == t) ? qk[i] : 0xFFFFFFFFu;
            bc = umin2(bc, x);
        }
        return bc;
    };
    unsigned bc0 = localbest(0), bc1 = localbest(1);
    unsigned bc2 = localbest(2), bc3 = localbest(3);
    unsigned bc4 = localbest(4), bc5 = localbest(5);
    unsigned bc6 = localbest(6), bc7 = localbest(7);

    // ---- butterfly min over the quad: 2 DPP + 2 min per target ----
    auto quadmin = [](unsigned v) -> unsigned {
        v = umin2(v, dpp_xor1_u(v));
        v = umin2(v, dpp_xor2_u(v));
        return v;
    };
    bc0 = quadmin(bc0); bc1 = quadmin(bc1);
    bc2 = quadmin(bc2); bc3 = quadmin(bc3);
    bc4 = quadmin(bc4); bc5 = quadmin(bc5);
    bc6 = quadmin(bc6); bc7 = quadmin(bc7);

    // ---- per-query label + guard ----
    // select bc[ind[i]] via 3-level cndmask tree (scalars only)
    auto selbc = [&](int id) -> unsigned {
        unsigned a0 = (id & 1) ? bc1 : bc0;
        unsigned a1 = (id & 1) ? bc3 : bc2;
        unsigned a2 = (id & 1) ? bc5 : bc4;
        unsigned a3 = (id & 1) ? bc7 : bc6;
        unsigned c0 = (id & 2) ? a1 : a0;
        unsigned c1 = (id & 2) ? a3 : a2;
        return (id & 4) ? c1 : c0;
    };

    bool  ns = false;
    float lab0, lab1, lab2, lab3;
    {
        float labs[4];
#pragma unroll
        for (int i = 0; i < 4; ++i) {
            unsigned bsel = selbc(ind[i]);
            bool isw = (qk[i] == bsel);
            // guard in float domain: non-winner within thr of its target's
            // best -> ambiguous under fast sigmoid + 5-bit key clearing.
            float Cf  = unordf(qk[i]);
            float bf  = unordf(bsel);
            float thr = fmaf(fabsf(bf), 1.6e-5f, 2.0e-4f);
            ns = ns || (!isw && ((Cf - bf) < thr));
            labs[i] = isw ? 1.0f : 0.0f;
        }
        lab0 = labs[0]; lab1 = labs[1]; lab2 = labs[2]; lab3 = labs[3];
    }

    // OR-reduce need_slow over the quad -> uniform branch, no divergence
    unsigned nsw = ns ? 1u : 0u;
    nsw |= dpp_xor1_u(nsw);
    nsw |= dpp_xor2_u(nsw);
    if (__builtin_expect(nsw != 0u, 0)) {
        unsigned mask = exact_mask(pred_logits, pred_disp, targets, b);
        lab0 = (float)((mask >> (4 * j + 0)) & 1u);
        lab1 = (float)((mask >> (4 * j + 1)) & 1u);
        lab2 = (float)((mask >> (4 * j + 2)) & 1u);
        lab3 = (float)((mask >> (4 * j + 3)) & 1u);
    }

    // ---- emit my 4 queries: 16 B/lane contiguous ----
    f32x4 oi, ol;
    oi.x = (float)ind[0]; oi.y = (float)ind[1];
    oi.z = (float)ind[2]; oi.w = (float)ind[3];
    ol.x = lab0; ol.y = lab1; ol.z = lab2; ol.w = lab3;
    ((f32x4*)out_idx)[gid] = oi;
    ((f32x4*)out_lab)[gid] = ol;
}

extern "C" void kernel_launch(void* const* d_in, const int* in_sizes, int n_in,
                              void* d_out, int out_size, void* d_ws, size_t ws_size,
                              hipStream_t stream) {
    const float* pred_logits = (const float*)d_in[0];
    const float* pred_disp   = (const float*)d_in[1];
    const float* targets     = (const float*)d_in[2];

    int B = in_sizes[0] / NQ;

    float* out_idx = (float*)d_out;              // indices [B, NQ] flat, first
    float* out_lab = out_idx + (size_t)B * NQ;   // labels  [B, NQ] flat, second

    const int threads = 1024;                    // 16 waves per workgroup
    const size_t total = (size_t)B * 4;          // 4 lanes per row
    const int blocks = (int)((total + threads - 1) / threads);
    hipLaunchKernelGGL(nearest_matcher_kernel, dim3(blocks), dim3(threads), 0, stream,
                       pred_logits, pred_disp, targets, out_idx, out_lab, B);
}